// Round 17
// baseline (107.230 us; speedup 1.0000x reference)
//
#include <hip/hip_runtime.h>

#define GROUP 8
#define BS 4096
#define CH 512
#define PW 32
#define NPANEL 16

typedef __attribute__((ext_vector_type(4))) float f32x4;
typedef __attribute__((ext_vector_type(8))) short bf16x8;
typedef __attribute__((ext_vector_type(8))) unsigned short u16x8;
typedef unsigned short u16;

static __device__ __forceinline__ u16 f2bf(float f) {
    unsigned int u = __builtin_bit_cast(unsigned int, f);
    u += 0x7FFFu + ((u >> 16) & 1u);   // RNE
    return (u16)(u >> 16);
}
static __device__ __forceinline__ float bf2f(u16 h) {
    return __builtin_bit_cast(float, (unsigned int)h << 16);
}
static __device__ __forceinline__ void split8(const float* v, bf16x8& h, bf16x8& l) {
#pragma unroll
    for (int j = 0; j < 8; ++j) {
        u16 hu = f2bf(v[j]);
        h[j] = (short)hu;
        l[j] = (short)f2bf(v[j] - bf2f(hu));
    }
}
#define MFMA(a, b, c) __builtin_amdgcn_mfma_f32_16x16x32_bf16(a, b, c, 0, 0, 0)

typedef const __attribute__((address_space(1))) void* gas_t;
typedef __attribute__((address_space(3))) void* las_t;
static __device__ __forceinline__ void gload16(const void* g, void* l) {
    __builtin_amdgcn_global_load_lds((gas_t)g, (las_t)l, 16, 0, 0);
}

// xcast slice: convert 1024 8-elem units starting at base (one group = 256
// blocks' worth of 1024-unit chunks).
static __device__ __forceinline__ void xcast_chunk(const float* __restrict__ x,
                                                   u16* __restrict__ xb,
                                                   int base, int t, int nthr) {
    for (int u = t; u < 1024; u += nthr) {
        int i = base + u;
        const float4* s = (const float4*)(x + (size_t)i * 8);
        float4 a = s[0], b = s[1];
        u16x8 o;
        o[0] = f2bf(a.x); o[1] = f2bf(a.y); o[2] = f2bf(a.z); o[3] = f2bf(a.w);
        o[4] = f2bf(b.x); o[5] = f2bf(b.y); o[6] = f2bf(b.z); o[7] = f2bf(b.w);
        *(u16x8*)(xb + (size_t)i * 8) = o;
    }
}
#define UPG 262144   // 8-elem units per group

// Yf: B-frag tiles over k=c. tile (it<32, ct<16); off = (it*16+ct)*512 + lane*8.
// Mf: B-frag tiles over k=i. tile (kt<16, ct<32);
//   off(i,c) = (kt*32+ct)*512 + ((i>>3)&3)*128 + (c&15)*8 + (i&7).
// Af: A-frag tiles (m=c, k=i). tile (kt<16, mt<32); off = (kt*32+mt)*512 + lane*8.
// XCD swizzle: group g owns XCD g across prep chain and gemm.
// xcast is SPREAD: panelprep does groups 0-2, combines 3-6, qbuild2 7.

// ---------------------------------------------------------------------------
// Kernel 1: per-32-panel prep, 1024 thr. Blocks 0..127: prep (XCD-swizzled).
// Blocks 128..895 (fat only): xcast groups 0..2.
// ---------------------------------------------------------------------------
__global__ __launch_bounds__(1024) void k_panelprep(const float* __restrict__ w,
                                                    const float* __restrict__ x,
                                                    u16* __restrict__ Yfh,
                                                    u16* __restrict__ Yfl,
                                                    u16* __restrict__ Mfh,
                                                    u16* __restrict__ Mfl,
                                                    u16* __restrict__ Afh,
                                                    u16* __restrict__ Afl,
                                                    u16* __restrict__ xb) {
    __shared__ float Ylds[PW][516];
    __shared__ float Sp[16][PW][36];     // reused as M staging after S-reduce
    __shared__ float S_ls[PW][36];
    __shared__ float T_ls[PW][36];

    int bid = blockIdx.x;
    int t   = threadIdx.x;

    if (bid >= 128) {
        int b = bid - 128;                       // 0..767
        int gs = b >> 8, j = b & 255;            // groups 0..2
        xcast_chunk(x, xb, gs * UPG + j * 1024, t, 1024);
        return;
    }

    int pb   = (bid & 7) * 16 + (bid >> 3);   // XCD-chunked (128%8==0)
    int lane = t & 63;
    int wv   = t >> 6;
    int fr   = lane & 15;
    int kg   = lane >> 4;
    int g    = pb >> 4;
    int p    = pb & 15;
    int i0   = p * PW;

    const float* wg = w + (size_t)g * CH * CH;
    for (int idx4 = t; idx4 < 4096; idx4 += 1024) {
        int c = idx4 >> 3, f4 = idx4 & 7;
        float4 v = *(const float4*)(wg + (size_t)c * CH + i0 + f4 * 4);
        Ylds[f4 * 4 + 0][c] = v.x;
        Ylds[f4 * 4 + 1][c] = v.y;
        Ylds[f4 * 4 + 2][c] = v.z;
        Ylds[f4 * 4 + 3][c] = v.w;
    }
    __syncthreads();

    {
        f32x4 sacc[2][2];
#pragma unroll
        for (int a = 0; a < 2; ++a)
#pragma unroll
            for (int b = 0; b < 2; ++b)
#pragma unroll
                for (int z = 0; z < 4; ++z) sacc[a][b][z] = 0.f;
        {
            int kk = wv;
            bf16x8 fh[2], fl[2];
#pragma unroll
            for (int h = 0; h < 2; ++h) {
                float a8[8];
                const float* src = &Ylds[h * 16 + fr][kk * 32 + kg * 8];
#pragma unroll
                for (int j = 0; j < 8; ++j) a8[j] = src[j];
                split8(a8, fh[h], fl[h]);
            }
#pragma unroll
            for (int a = 0; a < 2; ++a)
#pragma unroll
                for (int b = 0; b < 2; ++b) {
                    sacc[a][b] = MFMA(fh[a], fh[b], sacc[a][b]);
                    sacc[a][b] = MFMA(fh[a], fl[b], sacc[a][b]);
                    sacc[a][b] = MFMA(fl[a], fh[b], sacc[a][b]);
                }
        }
#pragma unroll
        for (int a = 0; a < 2; ++a)
#pragma unroll
            for (int b = 0; b < 2; ++b)
#pragma unroll
                for (int j = 0; j < 4; ++j)
                    Sp[wv][a * 16 + kg * 4 + j][b * 16 + fr] = sacc[a][b][j];
    }
    __syncthreads();
    for (int idx = t; idx < PW * PW; idx += 1024) {
        int r = idx >> 5, c = idx & 31;
        float s = 0.f;
#pragma unroll
        for (int q = 0; q < 16; ++q) s += Sp[q][r][c];
        S_ls[r][c] = s;
    }
    __syncthreads();

    if (wv == 0) {
        float Trow[PW];
#pragma unroll
        for (int j = 0; j < PW; ++j) Trow[j] = 0.f;
        if (lane < PW) Trow[lane] = 2.0f / S_ls[lane][lane];
#pragma unroll
        for (int k = 1; k < PW; ++k) {
            float acc = 0.f;
#pragma unroll
            for (int j = 0; j < PW; ++j)
                if (j < k) acc += Trow[j] * S_ls[j][k];
            float bk = 2.0f / S_ls[k][k];
            if (lane < k) Trow[k] = -bk * acc;
        }
        if (lane < PW)
#pragma unroll
            for (int j = 0; j < PW; ++j) T_ls[lane][j] = Trow[j];
    }
    __syncthreads();

    // ---- M^T = Y^T * T^T; staged in LDS in exact Mf byte layout ----
    u16* Msth = (u16*)Sp;
    u16* Mstl = Msth + 16384;
    {
        bf16x8 tbh[2], tbl[2];
#pragma unroll
        for (int cf = 0; cf < 2; ++cf) {
            float t8[8];
            const float* src = &T_ls[cf * 16 + fr][kg * 8];
#pragma unroll
            for (int j = 0; j < 8; ++j) t8[j] = src[j];
            split8(t8, tbh[cf], tbl[cf]);
        }
#pragma unroll
        for (int rfi = 0; rfi < 2; ++rfi) {
            int rf = 2 * wv + rfi;
            float a8[8];
#pragma unroll
            for (int j = 0; j < 8; ++j) a8[j] = Ylds[kg * 8 + j][rf * 16 + fr];
            bf16x8 ah, al;
            split8(a8, ah, al);
#pragma unroll
            for (int cf = 0; cf < 2; ++cf) {
                f32x4 m;
#pragma unroll
                for (int z = 0; z < 4; ++z) m[z] = 0.f;
                m = MFMA(ah, tbh[cf], m);
                m = MFMA(ah, tbl[cf], m);
                m = MFMA(al, tbh[cf], m);
#pragma unroll
                for (int j = 0; j < 4; ++j) {
                    int c  = rf * 16 + kg * 4 + j;
                    int ii = cf * 16 + fr;
                    int off = ((c >> 4)) * 512 + ((ii >> 3) * 16 + (c & 15)) * 8 + (ii & 7);
                    u16 hu = f2bf(m[j]);
                    Msth[off] = hu;
                    Mstl[off] = f2bf(m[j] - bf2f(hu));
                }
            }
        }
    }
    __syncthreads();
    {
        u16* Mfh_g = Mfh + (size_t)g * CH * CH + (size_t)p * 16384;
        u16* Mfl_g = Mfl + (size_t)g * CH * CH + (size_t)p * 16384;
        for (int idx = t; idx < 2048; idx += 1024) {
            *(bf16x8*)(Mfh_g + (size_t)idx * 8) = *(const bf16x8*)(Msth + idx * 8);
            *(bf16x8*)(Mfl_g + (size_t)idx * 8) = *(const bf16x8*)(Mstl + idx * 8);
        }
    }

    // ---- export Y panel (Yf) ----
    {
        u16* Yfh_g = Yfh + (size_t)g * CH * CH;
        u16* Yfl_g = Yfl + (size_t)g * CH * CH;
        for (int idx = t; idx < 32 * 64; idx += 1024) {
            int tile = idx >> 6, l2 = idx & 63;
            int itl = tile >> 4, ct = tile & 15;
            int row = l2 & 15, kgg = l2 >> 4;
            float a8[8];
            const float* src = &Ylds[itl * 16 + row][ct * 32 + kgg * 8];
#pragma unroll
            for (int j = 0; j < 8; ++j) a8[j] = src[j];
            bf16x8 h, l;
            split8(a8, h, l);
            size_t off = ((size_t)((2 * p + itl) * 16 + ct)) * 512 + (size_t)l2 * 8;
            *(bf16x8*)(Yfh_g + off) = h;
            *(bf16x8*)(Yfl_g + off) = l;
        }
    }

    // ---- export Af ----
    {
        u16* Afh_g = Afh + (size_t)g * CH * CH;
        u16* Afl_g = Afl + (size_t)g * CH * CH;
        for (int idx = t; idx < 32 * 64; idx += 1024) {
            int mt = idx >> 6, l2 = idx & 63;
            int row = l2 & 15, kg2 = l2 >> 4;
            float a8[8];
#pragma unroll
            for (int j = 0; j < 8; ++j) a8[j] = Ylds[kg2 * 8 + j][mt * 16 + row];
            bf16x8 h, l;
            split8(a8, h, l);
            size_t off = ((size_t)(p * 32 + mt)) * 512 + (size_t)l2 * 8;
            *(bf16x8*)(Afh_g + off) = h;
            *(bf16x8*)(Afl_g + off) = l;
        }
    }
}

// ---------------------------------------------------------------------------
// Kernel 2 (x4 levels): WY merge, blocks 0..127 work (XCD-swizzled, 512 thr,
// 16-row strips, depth-1 prefetch). Blocks 128..383: xcast group XG.
// ---------------------------------------------------------------------------
template<int W, int XG>
__global__ __launch_bounds__(512) void k_combine(const u16* __restrict__ Yfh,
                                                 const u16* __restrict__ Yfl,
                                                 u16* __restrict__ Mfh,
                                                 u16* __restrict__ Mfl,
                                                 const float* __restrict__ x,
                                                 u16* __restrict__ xb) {
    constexpr int NF   = W / 16;
    constexpr int KSPL = (NF >= 8) ? 1 : 8 / NF;
    constexpr int CPW  = (NF + 7) / 8;

    __shared__ u16 MAh[16][520];
    __shared__ u16 MAl[16][520];
    __shared__ float Cl[16][W + 4];
    __shared__ float Cpart[(KSPL > 1) ? (KSPL - 1) : 1][16][W + 4];

    int bid = blockIdx.x;
    int t = threadIdx.x;

    if (bid >= 128) {
        xcast_chunk(x, xb, XG * UPG + (bid - 128) * 1024, t, 512);
        return;
    }

    int cb  = (bid & 7) * 16 + (bid >> 3);    // XCD-chunked
    int lane = t & 63, wv = t >> 6;
    int fr = lane & 15, kg = lane >> 4;
    int g  = cb >> 4;
    int sg = cb & 15;
    constexpr int SP = W / 16;
    int q  = sg / SP, rs = sg % SP;
    int i_top0 = 2 * q * W + rs * 16;
    int i_bot0 = 2 * q * W + W;

    const u16* Yfh_g = Yfh + (size_t)g * CH * CH;
    const u16* Yfl_g = Yfl + (size_t)g * CH * CH;
    u16* Mfh_g = Mfh + (size_t)g * CH * CH;
    u16* Mfl_g = Mfl + (size_t)g * CH * CH;

    int kt_top = i_top0 >> 5;
    int hh     = (i_top0 & 31) >> 3;

    for (int idx = t; idx < 1024; idx += 512) {
        int c = idx >> 1, sub = idx & 1;
        size_t off = ((size_t)(kt_top * 32 + (c >> 4))) * 512
                   + (size_t)((hh + sub) * 16 + (c & 15)) * 8;
        bf16x8 hv = *(const bf16x8*)(Mfh_g + off);
        bf16x8 lv = *(const bf16x8*)(Mfl_g + off);
#pragma unroll
        for (int j = 0; j < 8; ++j) {
            MAh[sub * 8 + j][c] = (u16)hv[j];
            MAl[sub * 8 + j][c] = (u16)lv[j];
        }
    }
    __syncthreads();

    int ibt = i_bot0 >> 4;

    if constexpr (KSPL == 1) {
        f32x4 accC[CPW];
#pragma unroll
        for (int nfi = 0; nfi < CPW; ++nfi)
#pragma unroll
            for (int z = 0; z < 4; ++z) accC[nfi][z] = 0.f;

        auto LOADY = [&](int ks, bf16x8* dh, bf16x8* dl) {
#pragma unroll
            for (int nfi = 0; nfi < CPW; ++nfi) {
                int nf = wv + 8 * nfi;
                size_t yo = ((size_t)((ibt + nf) * 16 + ks)) * 512 + (size_t)lane * 8;
                dh[nfi] = *(const bf16x8*)(Yfh_g + yo);
                dl[nfi] = *(const bf16x8*)(Yfl_g + yo);
            }
        };

        bf16x8 pbh[CPW], pbl[CPW];
        LOADY(0, pbh, pbl);
#pragma unroll
        for (int ks = 0; ks < 16; ++ks) {
            bf16x8 qbh[CPW], qbl[CPW];
            if (ks + 1 < 16) LOADY(ks + 1, qbh, qbl);
            bf16x8 ah = *(const bf16x8*)&MAh[fr][ks * 32 + kg * 8];
            bf16x8 al = *(const bf16x8*)&MAl[fr][ks * 32 + kg * 8];
#pragma unroll
            for (int nfi = 0; nfi < CPW; ++nfi) {
                accC[nfi] = MFMA(ah, pbh[nfi], accC[nfi]);
                accC[nfi] = MFMA(ah, pbl[nfi], accC[nfi]);
                accC[nfi] = MFMA(al, pbh[nfi], accC[nfi]);
            }
#pragma unroll
            for (int nfi = 0; nfi < CPW; ++nfi) { pbh[nfi] = qbh[nfi]; pbl[nfi] = qbl[nfi]; }
        }
#pragma unroll
        for (int nfi = 0; nfi < CPW; ++nfi) {
            int nf = wv + 8 * nfi;
#pragma unroll
            for (int jj = 0; jj < 4; ++jj)
                Cl[kg * 4 + jj][nf * 16 + fr] = accC[nfi][jj];
        }
        __syncthreads();
    } else {
        int nf  = wv % NF;
        int ksl = wv / NF;
        constexpr int KCH = 16 / KSPL;
        f32x4 accC;
#pragma unroll
        for (int z = 0; z < 4; ++z) accC[z] = 0.f;

        auto LOADY1 = [&](int ks, bf16x8& dh, bf16x8& dl) {
            size_t yo = ((size_t)((ibt + nf) * 16 + ks)) * 512 + (size_t)lane * 8;
            dh = *(const bf16x8*)(Yfh_g + yo);
            dl = *(const bf16x8*)(Yfl_g + yo);
        };

        bf16x8 pbh, pbl;
        LOADY1(ksl * KCH, pbh, pbl);
#pragma unroll
        for (int ki = 0; ki < KCH; ++ki) {
            int ks = ksl * KCH + ki;
            bf16x8 qbh, qbl;
            if (ki + 1 < KCH) LOADY1(ks + 1, qbh, qbl);
            bf16x8 ah = *(const bf16x8*)&MAh[fr][ks * 32 + kg * 8];
            bf16x8 al = *(const bf16x8*)&MAl[fr][ks * 32 + kg * 8];
            accC = MFMA(ah, pbh, accC);
            accC = MFMA(ah, pbl, accC);
            accC = MFMA(al, pbh, accC);
            pbh = qbh; pbl = qbl;
        }
        if (ksl == 0) {
#pragma unroll
            for (int jj = 0; jj < 4; ++jj)
                Cl[kg * 4 + jj][nf * 16 + fr] = accC[jj];
        } else {
#pragma unroll
            for (int jj = 0; jj < 4; ++jj)
                Cpart[ksl - 1][kg * 4 + jj][nf * 16 + fr] = accC[jj];
        }
        __syncthreads();
        for (int idx = t; idx < 16 * W; idx += 512) {
            int r = idx / W, c = idx - r * W;
            float s = Cl[r][c];
#pragma unroll
            for (int u = 0; u < KSPL - 1; ++u) s += Cpart[u][r][c];
            Cl[r][c] = s;
        }
        __syncthreads();
    }

    f32x4 accU[4];
#pragma unroll
    for (int ni = 0; ni < 4; ++ni)
#pragma unroll
        for (int z = 0; z < 4; ++z) accU[ni][z] = 0.f;

    int kt_bot = i_bot0 >> 5;
    constexpr int NKS2 = W / 32;

    auto LOADM = [&](int ks2, bf16x8* dh, bf16x8* dl) {
#pragma unroll
        for (int ni = 0; ni < 4; ++ni) {
            int ct = wv * 4 + ni;
            size_t mo = ((size_t)((kt_bot + ks2) * 32 + ct)) * 512 + (size_t)lane * 8;
            dh[ni] = *(const bf16x8*)(Mfh_g + mo);
            dl[ni] = *(const bf16x8*)(Mfl_g + mo);
        }
    };

    {
        bf16x8 mph[4], mpl[4];
        LOADM(0, mph, mpl);
#pragma unroll
        for (int ks2 = 0; ks2 < NKS2; ++ks2) {
            bf16x8 mqh[4], mql[4];
            if (ks2 + 1 < NKS2) LOADM(ks2 + 1, mqh, mql);
            float a8[8];
#pragma unroll
            for (int j = 0; j < 8; ++j) a8[j] = Cl[fr][ks2 * 32 + kg * 8 + j];
            bf16x8 ah2, al2;
            split8(a8, ah2, al2);
#pragma unroll
            for (int ni = 0; ni < 4; ++ni) {
                accU[ni] = MFMA(ah2, mph[ni], accU[ni]);
                accU[ni] = MFMA(ah2, mpl[ni], accU[ni]);
                accU[ni] = MFMA(al2, mph[ni], accU[ni]);
            }
#pragma unroll
            for (int ni = 0; ni < 4; ++ni) { mph[ni] = mqh[ni]; mpl[ni] = mql[ni]; }
        }
    }
#pragma unroll
    for (int ni = 0; ni < 4; ++ni) {
        int c = (wv * 4 + ni) * 16 + fr;
#pragma unroll
        for (int jj = 0; jj < 4; ++jj) {
            int il = kg * 4 + jj;
            float ma = bf2f(MAh[il][c]) + bf2f(MAl[il][c]);
            float m2 = ma - accU[ni][jj];
            u16 hu = f2bf(m2);
            MAh[il][c] = hu;
            MAl[il][c] = f2bf(m2 - bf2f(hu));
        }
    }
    __syncthreads();

    for (int idx = t; idx < 1024; idx += 512) {
        int c = idx >> 1, sub = idx & 1;
        bf16x8 hv, lv;
#pragma unroll
        for (int j = 0; j < 8; ++j) {
            hv[j] = (short)MAh[sub * 8 + j][c];
            lv[j] = (short)MAl[sub * 8 + j][c];
        }
        size_t off = ((size_t)(kt_top * 32 + (c >> 4))) * 512
                   + (size_t)((hh + sub) * 16 + (c & 15)) * 8;
        *(bf16x8*)(Mfh_g + off) = hv;
        *(bf16x8*)(Mfl_g + off) = lv;
    }
}

// ---------------------------------------------------------------------------
// Kernel 3: Qt build. Blocks 0..511 work (XCD-swizzled); 512..767: xcast grp 7.
// ---------------------------------------------------------------------------
__global__ __launch_bounds__(256) void k_qbuild2(const u16* __restrict__ Afh,
                                                 const u16* __restrict__ Afl,
                                                 const u16* __restrict__ Mfh,
                                                 const u16* __restrict__ Mfl,
                                                 u16* __restrict__ Qt,
                                                 const float* __restrict__ x,
                                                 u16* __restrict__ xb) {
    int bid = blockIdx.x;
    int t = threadIdx.x;

    if (bid >= 512) {
        xcast_chunk(x, xb, 7 * UPG + (bid - 512) * 1024, t, 256);
        return;
    }

    int qb  = (bid & 7) * 64 + (bid >> 3);    // XCD-chunked
    int lane = t & 63, wv = t >> 6;
    int fr = lane & 15, kg = lane >> 4;
    int g  = qb >> 6;
    int tm = (qb >> 2) & 15, tn = qb & 3;
    int c0 = tm * 32;
    int d0 = tn * 128 + wv * 32;

    const u16* Afh_g = Afh + (size_t)g * CH * CH;
    const u16* Afl_g = Afl + (size_t)g * CH * CH;
    const u16* Mfh_g = Mfh + (size_t)g * CH * CH;
    const u16* Mfl_g = Mfl + (size_t)g * CH * CH;
    u16* Qt_g = Qt + (size_t)g * CH * CH;

    f32x4 acc[2][2];
#pragma unroll
    for (int mi = 0; mi < 2; ++mi)
#pragma unroll
        for (int ni = 0; ni < 2; ++ni)
#pragma unroll
            for (int z = 0; z < 4; ++z) acc[mi][ni][z] = 0.f;

    int mt0 = c0 >> 4;
    for (int ks = 0; ks < 16; ++ks) {
        bf16x8 ah[2], al[2], bh[2], bl[2];
#pragma unroll
        for (int mi = 0; mi < 2; ++mi) {
            size_t ao = ((size_t)(ks * 32 + mt0 + mi)) * 512 + (size_t)lane * 8;
            ah[mi] = *(const bf16x8*)(Afh_g + ao);
            al[mi] = *(const bf16x8*)(Afl_g + ao);
        }
#pragma unroll
        for (int ni = 0; ni < 2; ++ni) {
            int ct = (d0 >> 4) + ni;
            size_t mo = ((size_t)(ks * 32 + ct)) * 512 + (size_t)lane * 8;
            bh[ni] = *(const bf16x8*)(Mfh_g + mo);
            bl[ni] = *(const bf16x8*)(Mfl_g + mo);
        }
#pragma unroll
        for (int mi = 0; mi < 2; ++mi)
#pragma unroll
            for (int ni = 0; ni < 2; ++ni) {
                acc[mi][ni] = MFMA(ah[mi], bh[ni], acc[mi][ni]);
                acc[mi][ni] = MFMA(ah[mi], bl[ni], acc[mi][ni]);
                acc[mi][ni] = MFMA(al[mi], bh[ni], acc[mi][ni]);
            }
    }
#pragma unroll
    for (int mi = 0; mi < 2; ++mi)
#pragma unroll
        for (int ni = 0; ni < 2; ++ni) {
            int cb2 = c0 + mi * 16 + kg * 4;
            int d   = d0 + ni * 16 + fr;
            ushort4 h4;
            h4.x = f2bf(((cb2 + 0 == d) ? 1.0f : 0.0f) - acc[mi][ni][0]);
            h4.y = f2bf(((cb2 + 1 == d) ? 1.0f : 0.0f) - acc[mi][ni][1]);
            h4.z = f2bf(((cb2 + 2 == d) ? 1.0f : 0.0f) - acc[mi][ni][2]);
            h4.w = f2bf(((cb2 + 3 == d) ? 1.0f : 0.0f) - acc[mi][ni][3]);
            *(ushort4*)(Qt_g + (size_t)d * CH + cb2) = h4;
        }
}

// ---------------------------------------------------------------------------
// Kernel 4: dbuf GEMM, counted vmcnt (T4) + setprio (T5). BK=32. (round-16)
// ---------------------------------------------------------------------------
__global__ __launch_bounds__(256) void k_gemm2(const u16* __restrict__ xb,
                                               const u16* __restrict__ Qt,
                                               float* __restrict__ out) {
    __shared__ u16 Ab[2][128 * 32];
    __shared__ u16 Bb[2][128 * 32];

    int bid0 = blockIdx.x;
    int wg = (bid0 & 7) * 128 + (bid0 >> 3);  // bijective XCD chunk; g == bid0&7
    int g  = wg >> 7;
    int r  = wg & 127;
    int tm = r >> 2;
    int tn = r & 3;

    int t    = threadIdx.x;
    int lane = t & 63;
    int wv   = t >> 6;
    int wr   = wv >> 1, wc = wv & 1;
    int fr   = lane & 15, kg = lane >> 4;

    const u16* xg  = xb + (size_t)g * BS * CH + (size_t)tm * 128 * CH;
    const u16* Qtg = Qt + (size_t)g * CH * CH + (size_t)tn * 128 * CH;
    float* og = out + (size_t)g * BS * CH + (size_t)tm * 128 * CH + (size_t)tn * 128;

    f32x4 acc[4][4];
#pragma unroll
    for (int mi = 0; mi < 4; ++mi)
#pragma unroll
        for (int ni = 0; ni < 4; ++ni)
#pragma unroll
            for (int z = 0; z < 4; ++z) acc[mi][ni][z] = 0.f;

    int srow = lane >> 2;
    int scol = (lane & 3) * 8;

    auto STAGE = [&](int p, int ks) {
        int k0 = ks * 32;
#pragma unroll
        for (int si = 0; si < 2; ++si) {
            int seg = wv * 2 + si;
            int row = seg * 16 + srow;
            gload16(xg  + (size_t)row * CH + k0 + scol, &Ab[p][seg * 512]);
            gload16(Qtg + (size_t)row * CH + k0 + scol, &Bb[p][seg * 512]);
        }
    };

    STAGE(0, 0);
    asm volatile("s_waitcnt vmcnt(0)" ::: "memory");
    __builtin_amdgcn_s_barrier();

    for (int ks = 0; ks < 16; ++ks) {
        int cur = ks & 1;
        if (ks < 15) {
            STAGE(cur ^ 1, ks + 1);
            asm volatile("s_waitcnt vmcnt(4)" ::: "memory");
        } else {
            asm volatile("s_waitcnt vmcnt(0)" ::: "memory");
        }
        __builtin_amdgcn_s_barrier();

        bf16x8 af[4], bfr[4];
#pragma unroll
        for (int mi = 0; mi < 4; ++mi)
            af[mi] = *(const bf16x8*)&Ab[cur][(wr * 64 + mi * 16 + fr) * 32 + kg * 8];
#pragma unroll
        for (int ni = 0; ni < 4; ++ni)
            bfr[ni] = *(const bf16x8*)&Bb[cur][(wc * 64 + ni * 16 + fr) * 32 + kg * 8];
        __builtin_amdgcn_s_setprio(1);
#pragma unroll
        for (int mi = 0; mi < 4; ++mi)
#pragma unroll
            for (int ni = 0; ni < 4; ++ni)
                acc[mi][ni] = MFMA(af[mi], bfr[ni], acc[mi][ni]);
        __builtin_amdgcn_s_setprio(0);

        asm volatile("" ::: "memory");
        __builtin_amdgcn_s_barrier();
    }

    int rg = lane >> 4;
#pragma unroll
    for (int mi = 0; mi < 4; ++mi)
#pragma unroll
        for (int ni = 0; ni < 4; ++ni)
#pragma unroll
            for (int rj = 0; rj < 4; ++rj) {
                int grow = wr * 64 + mi * 16 + rg * 4 + rj;
                int gcol = wc * 64 + ni * 16 + fr;
                og[(size_t)grow * CH + gcol] = acc[mi][ni][rj];
            }
}

// ---------------------------------------------------------------------------
// Fallback GEMM (fp32 A, in-staging convert) — round-5 verified.
// ---------------------------------------------------------------------------
#define LDP 40
__global__ __launch_bounds__(256) void k_gemm_f32(const float* __restrict__ x,
                                                  const u16* __restrict__ Qt,
                                                  float* __restrict__ out) {
    __shared__ u16 Al[128 * LDP];
    __shared__ u16 Bl[128 * LDP];

    int bid = blockIdx.x;
    int g  = bid >> 7;
    int tn = (bid >> 5) & 3;
    int tm = bid & 31;

    int t    = threadIdx.x;
    int lane = t & 63;
    int w    = t >> 6;
    int wr   = w >> 1, wc = w & 1;

    const float* xg = x + (size_t)g * BS * CH + (size_t)tm * 128 * CH;
    const u16* Qtg = Qt + (size_t)g * CH * CH + (size_t)tn * 128 * CH;
    float* og = out + (size_t)g * BS * CH + (size_t)tm * 128 * CH + (size_t)tn * 128;

    f32x4 acc[4][4];
#pragma unroll
    for (int mi = 0; mi < 4; ++mi)
#pragma unroll
        for (int ni = 0; ni < 4; ++ni)
#pragma unroll
            for (int z = 0; z < 4; ++z) acc[mi][ni][z] = 0.f;

    int a_k4 = t & 7;
    int a_r  = t >> 3;
    int b_n  = t & 127;
    int b_kh = t >> 7;
    int fr = lane & 15, kg = lane >> 4;

    for (int ks = 0; ks < 16; ++ks) {
        int k0 = ks * 32;
        __syncthreads();
#pragma unroll
        for (int rr = 0; rr < 4; ++rr) {
            int r = a_r + 32 * rr;
            float4 v = *(const float4*)(xg + (size_t)r * CH + k0 + a_k4 * 4);
            ushort4 h;
            h.x = f2bf(v.x); h.y = f2bf(v.y); h.z = f2bf(v.z); h.w = f2bf(v.w);
            *(ushort4*)(&Al[r * LDP + a_k4 * 4]) = h;
        }
        {
            const u16* src = Qtg + (size_t)b_n * CH + k0 + b_kh * 16;
            u16x8 lo = *(const u16x8*)src;
            u16x8 hi = *(const u16x8*)(src + 8);
            *(u16x8*)(&Bl[b_n * LDP + b_kh * 16]) = lo;
            *(u16x8*)(&Bl[b_n * LDP + b_kh * 16 + 8]) = hi;
        }
        __syncthreads();
        bf16x8 af[4], bfr[4];
#pragma unroll
        for (int mi = 0; mi < 4; ++mi)
            af[mi] = *(const bf16x8*)(&Al[(wr * 64 + mi * 16 + fr) * LDP + kg * 8]);
#pragma unroll
        for (int ni = 0; ni < 4; ++ni)
            bfr[ni] = *(const bf16x8*)(&Bl[(wc * 64 + ni * 16 + fr) * LDP + kg * 8]);
#pragma unroll
        for (int mi = 0; mi < 4; ++mi)
#pragma unroll
            for (int ni = 0; ni < 4; ++ni)
                acc[mi][ni] = MFMA(af[mi], bfr[ni], acc[mi][ni]);
    }

    int rg = lane >> 4;
#pragma unroll
    for (int mi = 0; mi < 4; ++mi)
#pragma unroll
        for (int ni = 0; ni < 4; ++ni)
#pragma unroll
            for (int rj = 0; rj < 4; ++rj) {
                int grow = wr * 64 + mi * 16 + rg * 4 + rj;
                int gcol = wc * 64 + ni * 16 + fr;
                og[(size_t)grow * CH + gcol] = acc[mi][ni][rj];
            }
}

// ---------------------------------------------------------------------------
extern "C" void kernel_launch(void* const* d_in, const int* in_sizes, int n_in,
                              void* d_out, int out_size, void* d_ws, size_t ws_size,
                              hipStream_t stream) {
    const float* x = (const float*)d_in[0];   // (8, 4096, 512)
    const float* w = (const float*)d_in[1];   // (8, 512, 512)
    float* out = (float*)d_out;

    char* ob = (char*)d_out;                  // 64 MiB scratch, dead before GEMM
    u16* Yfh = (u16*)ob;                      // [0, 4MB)
    u16* Yfl = (u16*)(ob + (4u  << 20));      // [4, 8)
    u16* Mfh = (u16*)(ob + (8u  << 20));      // [8, 12)
    u16* Mfl = (u16*)(ob + (12u << 20));      // [12, 16)
    u16* Afh = (u16*)(ob + (16u << 20));      // [16, 20)
    u16* Afl = (u16*)(ob + (20u << 20));      // [20, 24)

    int fat = (ws_size >= ((32u << 20) + (4u << 20))) ? 1 : 0;
    u16* xbp = (u16*)d_ws;
    u16* Qt  = fat ? (u16*)((char*)d_ws + (32u << 20)) : (u16*)d_ws;

    k_panelprep<<<dim3(fat ? 896 : 128), dim3(1024), 0, stream>>>(w, x, Yfh, Yfl, Mfh, Mfl, Afh, Afl, xbp);
    k_combine<32, 3><<<dim3(fat ? 384 : 128), dim3(512), 0, stream>>>(Yfh, Yfl, Mfh, Mfl, x, xbp);
    k_combine<64, 4><<<dim3(fat ? 384 : 128), dim3(512), 0, stream>>>(Yfh, Yfl, Mfh, Mfl, x, xbp);
    k_combine<128, 5><<<dim3(fat ? 384 : 128), dim3(512), 0, stream>>>(Yfh, Yfl, Mfh, Mfl, x, xbp);
    k_combine<256, 6><<<dim3(fat ? 384 : 128), dim3(512), 0, stream>>>(Yfh, Yfl, Mfh, Mfl, x, xbp);
    k_qbuild2<<<dim3(fat ? 768 : 512), dim3(256), 0, stream>>>(Afh, Afl, Mfh, Mfl, Qt, x, xbp);
    if (fat)
        k_gemm2<<<dim3(1024), dim3(256), 0, stream>>>(xbp, Qt, out);
    else
        k_gemm_f32<<<dim3(1024), dim3(256), 0, stream>>>(x, Qt, out);
}

// Round 18
// 102.758 us; speedup vs baseline: 1.0435x; 1.0435x over previous
//
#include <hip/hip_runtime.h>

#define GROUP 8
#define BS 4096
#define CH 512
#define PW 32
#define NPANEL 16

typedef __attribute__((ext_vector_type(4))) float f32x4;
typedef __attribute__((ext_vector_type(8))) short bf16x8;
typedef __attribute__((ext_vector_type(8))) unsigned short u16x8;
typedef unsigned short u16;

static __device__ __forceinline__ u16 f2bf(float f) {
    unsigned int u = __builtin_bit_cast(unsigned int, f);
    u += 0x7FFFu + ((u >> 16) & 1u);   // RNE
    return (u16)(u >> 16);
}
static __device__ __forceinline__ float bf2f(u16 h) {
    return __builtin_bit_cast(float, (unsigned int)h << 16);
}
static __device__ __forceinline__ void split8(const float* v, bf16x8& h, bf16x8& l) {
#pragma unroll
    for (int j = 0; j < 8; ++j) {
        u16 hu = f2bf(v[j]);
        h[j] = (short)hu;
        l[j] = (short)f2bf(v[j] - bf2f(hu));
    }
}
#define MFMA(a, b, c) __builtin_amdgcn_mfma_f32_16x16x32_bf16(a, b, c, 0, 0, 0)

typedef const __attribute__((address_space(1))) void* gas_t;
typedef __attribute__((address_space(3))) void* las_t;
static __device__ __forceinline__ void gload16(const void* g, void* l) {
    __builtin_amdgcn_global_load_lds((gas_t)g, (las_t)l, 16, 0, 0);
}

// Yf: B-frag tiles over k=c. tile (it<32, ct<16); off = (it*16+ct)*512 + lane*8.
// Mf: B-frag tiles over k=i. tile (kt<16, ct<32);
//   off(i,c) = (kt*32+ct)*512 + ((i>>3)&3)*128 + (c&15)*8 + (i&7).
// Af: A-frag tiles (m=c, k=i). tile (kt<16, mt<32); off = (kt*32+mt)*512 + lane*8.
// XCD swizzle convention: group g owns XCD g across prep chain, xcast, gemm.

// ---------------------------------------------------------------------------
// Kernel 1: per-32-panel prep, 1024 thr. Blocks 0..127: prep (XCD-swizzled).
// Blocks 128..1151 (fat only): x fp32->bf16 cast, group g on XCD g.
// ---------------------------------------------------------------------------
__global__ __launch_bounds__(1024) void k_panelprep(const float* __restrict__ w,
                                                    const float* __restrict__ x,
                                                    u16* __restrict__ Yfh,
                                                    u16* __restrict__ Yfl,
                                                    u16* __restrict__ Mfh,
                                                    u16* __restrict__ Mfl,
                                                    u16* __restrict__ Afh,
                                                    u16* __restrict__ Afl,
                                                    u16* __restrict__ xb) {
    __shared__ float Ylds[PW][516];
    __shared__ float Sp[16][PW][36];     // reused as M staging after S-reduce
    __shared__ float S_ls[PW][36];
    __shared__ float T_ls[PW][36];

    int bid = blockIdx.x;
    int t   = threadIdx.x;

    if (bid >= 128) {
        int bx  = bid - 128;                       // 0..1023
        int xcd = bx & 7;
        int j   = bx >> 3;                         // 0..127
        const int UPG = (BS * CH) / 8;             // 262144 units per group
        int base = xcd * UPG + j * (UPG / 128);    // 2048 units per block
        for (int u = t; u < 2048; u += 1024) {
            int i = base + u;
            const float4* s = (const float4*)(x + (size_t)i * 8);
            float4 a = s[0], b = s[1];
            u16x8 o;
            o[0] = f2bf(a.x); o[1] = f2bf(a.y); o[2] = f2bf(a.z); o[3] = f2bf(a.w);
            o[4] = f2bf(b.x); o[5] = f2bf(b.y); o[6] = f2bf(b.z); o[7] = f2bf(b.w);
            *(u16x8*)(xb + (size_t)i * 8) = o;
        }
        return;
    }

    int pb   = (bid & 7) * 16 + (bid >> 3);   // XCD-chunked (128%8==0)
    int lane = t & 63;
    int wv   = t >> 6;
    int fr   = lane & 15;
    int kg   = lane >> 4;
    int g    = pb >> 4;
    int p    = pb & 15;
    int i0   = p * PW;

    const float* wg = w + (size_t)g * CH * CH;
    for (int idx4 = t; idx4 < 4096; idx4 += 1024) {
        int c = idx4 >> 3, f4 = idx4 & 7;
        float4 v = *(const float4*)(wg + (size_t)c * CH + i0 + f4 * 4);
        Ylds[f4 * 4 + 0][c] = v.x;
        Ylds[f4 * 4 + 1][c] = v.y;
        Ylds[f4 * 4 + 2][c] = v.z;
        Ylds[f4 * 4 + 3][c] = v.w;
    }
    __syncthreads();

    {
        f32x4 sacc[2][2];
#pragma unroll
        for (int a = 0; a < 2; ++a)
#pragma unroll
            for (int b = 0; b < 2; ++b)
#pragma unroll
                for (int z = 0; z < 4; ++z) sacc[a][b][z] = 0.f;
        {
            int kk = wv;
            bf16x8 fh[2], fl[2];
#pragma unroll
            for (int h = 0; h < 2; ++h) {
                float a8[8];
                const float* src = &Ylds[h * 16 + fr][kk * 32 + kg * 8];
#pragma unroll
                for (int j = 0; j < 8; ++j) a8[j] = src[j];
                split8(a8, fh[h], fl[h]);
            }
#pragma unroll
            for (int a = 0; a < 2; ++a)
#pragma unroll
                for (int b = 0; b < 2; ++b) {
                    sacc[a][b] = MFMA(fh[a], fh[b], sacc[a][b]);
                    sacc[a][b] = MFMA(fh[a], fl[b], sacc[a][b]);
                    sacc[a][b] = MFMA(fl[a], fh[b], sacc[a][b]);
                }
        }
#pragma unroll
        for (int a = 0; a < 2; ++a)
#pragma unroll
            for (int b = 0; b < 2; ++b)
#pragma unroll
                for (int j = 0; j < 4; ++j)
                    Sp[wv][a * 16 + kg * 4 + j][b * 16 + fr] = sacc[a][b][j];
    }
    __syncthreads();
    for (int idx = t; idx < PW * PW; idx += 1024) {
        int r = idx >> 5, c = idx & 31;
        float s = 0.f;
#pragma unroll
        for (int q = 0; q < 16; ++q) s += Sp[q][r][c];
        S_ls[r][c] = s;
    }
    __syncthreads();

    if (wv == 0) {
        float Trow[PW];
#pragma unroll
        for (int j = 0; j < PW; ++j) Trow[j] = 0.f;
        if (lane < PW) Trow[lane] = 2.0f / S_ls[lane][lane];
#pragma unroll
        for (int k = 1; k < PW; ++k) {
            float acc = 0.f;
#pragma unroll
            for (int j = 0; j < PW; ++j)
                if (j < k) acc += Trow[j] * S_ls[j][k];
            float bk = 2.0f / S_ls[k][k];
            if (lane < k) Trow[k] = -bk * acc;
        }
        if (lane < PW)
#pragma unroll
            for (int j = 0; j < PW; ++j) T_ls[lane][j] = Trow[j];
    }
    __syncthreads();

    // ---- M^T = Y^T * T^T; staged in LDS in exact Mf byte layout ----
    u16* Msth = (u16*)Sp;
    u16* Mstl = Msth + 16384;
    {
        bf16x8 tbh[2], tbl[2];
#pragma unroll
        for (int cf = 0; cf < 2; ++cf) {
            float t8[8];
            const float* src = &T_ls[cf * 16 + fr][kg * 8];
#pragma unroll
            for (int j = 0; j < 8; ++j) t8[j] = src[j];
            split8(t8, tbh[cf], tbl[cf]);
        }
#pragma unroll
        for (int rfi = 0; rfi < 2; ++rfi) {
            int rf = 2 * wv + rfi;
            float a8[8];
#pragma unroll
            for (int j = 0; j < 8; ++j) a8[j] = Ylds[kg * 8 + j][rf * 16 + fr];
            bf16x8 ah, al;
            split8(a8, ah, al);
#pragma unroll
            for (int cf = 0; cf < 2; ++cf) {
                f32x4 m;
#pragma unroll
                for (int z = 0; z < 4; ++z) m[z] = 0.f;
                m = MFMA(ah, tbh[cf], m);
                m = MFMA(ah, tbl[cf], m);
                m = MFMA(al, tbh[cf], m);
#pragma unroll
                for (int j = 0; j < 4; ++j) {
                    int c  = rf * 16 + kg * 4 + j;
                    int ii = cf * 16 + fr;
                    int off = ((c >> 4)) * 512 + ((ii >> 3) * 16 + (c & 15)) * 8 + (ii & 7);
                    u16 hu = f2bf(m[j]);
                    Msth[off] = hu;
                    Mstl[off] = f2bf(m[j] - bf2f(hu));
                }
            }
        }
    }
    __syncthreads();
    {
        u16* Mfh_g = Mfh + (size_t)g * CH * CH + (size_t)p * 16384;
        u16* Mfl_g = Mfl + (size_t)g * CH * CH + (size_t)p * 16384;
        for (int idx = t; idx < 2048; idx += 1024) {
            *(bf16x8*)(Mfh_g + (size_t)idx * 8) = *(const bf16x8*)(Msth + idx * 8);
            *(bf16x8*)(Mfl_g + (size_t)idx * 8) = *(const bf16x8*)(Mstl + idx * 8);
        }
    }

    // ---- export Y panel (Yf) ----
    {
        u16* Yfh_g = Yfh + (size_t)g * CH * CH;
        u16* Yfl_g = Yfl + (size_t)g * CH * CH;
        for (int idx = t; idx < 32 * 64; idx += 1024) {
            int tile = idx >> 6, l2 = idx & 63;
            int itl = tile >> 4, ct = tile & 15;
            int row = l2 & 15, kgg = l2 >> 4;
            float a8[8];
            const float* src = &Ylds[itl * 16 + row][ct * 32 + kgg * 8];
#pragma unroll
            for (int j = 0; j < 8; ++j) a8[j] = src[j];
            bf16x8 h, l;
            split8(a8, h, l);
            size_t off = ((size_t)((2 * p + itl) * 16 + ct)) * 512 + (size_t)l2 * 8;
            *(bf16x8*)(Yfh_g + off) = h;
            *(bf16x8*)(Yfl_g + off) = l;
        }
    }

    // ---- export Af ----
    {
        u16* Afh_g = Afh + (size_t)g * CH * CH;
        u16* Afl_g = Afl + (size_t)g * CH * CH;
        for (int idx = t; idx < 32 * 64; idx += 1024) {
            int mt = idx >> 6, l2 = idx & 63;
            int row = l2 & 15, kg2 = l2 >> 4;
            float a8[8];
#pragma unroll
            for (int j = 0; j < 8; ++j) a8[j] = Ylds[kg2 * 8 + j][mt * 16 + row];
            bf16x8 h, l;
            split8(a8, h, l);
            size_t off = ((size_t)(p * 32 + mt)) * 512 + (size_t)l2 * 8;
            *(bf16x8*)(Afh_g + off) = h;
            *(bf16x8*)(Afl_g + off) = l;
        }
    }
}

// ---------------------------------------------------------------------------
// Kernel 2 (x4 levels): WY merge, 128 blocks x 512 thr, 16-row strips,
// XCD-swizzled, depth-1 prefetch (round-16 verified).
// ---------------------------------------------------------------------------
template<int W>
__global__ __launch_bounds__(512) void k_combine(const u16* __restrict__ Yfh,
                                                 const u16* __restrict__ Yfl,
                                                 u16* __restrict__ Mfh,
                                                 u16* __restrict__ Mfl) {
    constexpr int NF   = W / 16;
    constexpr int KSPL = (NF >= 8) ? 1 : 8 / NF;
    constexpr int CPW  = (NF + 7) / 8;

    __shared__ u16 MAh[16][520];
    __shared__ u16 MAl[16][520];
    __shared__ float Cl[16][W + 4];
    __shared__ float Cpart[(KSPL > 1) ? (KSPL - 1) : 1][16][W + 4];

    int bid = blockIdx.x;
    int cb  = (bid & 7) * 16 + (bid >> 3);    // XCD-chunked
    int t = threadIdx.x, lane = t & 63, wv = t >> 6;
    int fr = lane & 15, kg = lane >> 4;
    int g  = cb >> 4;
    int sg = cb & 15;
    constexpr int SP = W / 16;
    int q  = sg / SP, rs = sg % SP;
    int i_top0 = 2 * q * W + rs * 16;
    int i_bot0 = 2 * q * W + W;

    const u16* Yfh_g = Yfh + (size_t)g * CH * CH;
    const u16* Yfl_g = Yfl + (size_t)g * CH * CH;
    u16* Mfh_g = Mfh + (size_t)g * CH * CH;
    u16* Mfl_g = Mfl + (size_t)g * CH * CH;

    int kt_top = i_top0 >> 5;
    int hh     = (i_top0 & 31) >> 3;

    for (int idx = t; idx < 1024; idx += 512) {
        int c = idx >> 1, sub = idx & 1;
        size_t off = ((size_t)(kt_top * 32 + (c >> 4))) * 512
                   + (size_t)((hh + sub) * 16 + (c & 15)) * 8;
        bf16x8 hv = *(const bf16x8*)(Mfh_g + off);
        bf16x8 lv = *(const bf16x8*)(Mfl_g + off);
#pragma unroll
        for (int j = 0; j < 8; ++j) {
            MAh[sub * 8 + j][c] = (u16)hv[j];
            MAl[sub * 8 + j][c] = (u16)lv[j];
        }
    }
    __syncthreads();

    int ibt = i_bot0 >> 4;

    if constexpr (KSPL == 1) {
        f32x4 accC[CPW];
#pragma unroll
        for (int nfi = 0; nfi < CPW; ++nfi)
#pragma unroll
            for (int z = 0; z < 4; ++z) accC[nfi][z] = 0.f;

        auto LOADY = [&](int ks, bf16x8* dh, bf16x8* dl) {
#pragma unroll
            for (int nfi = 0; nfi < CPW; ++nfi) {
                int nf = wv + 8 * nfi;
                size_t yo = ((size_t)((ibt + nf) * 16 + ks)) * 512 + (size_t)lane * 8;
                dh[nfi] = *(const bf16x8*)(Yfh_g + yo);
                dl[nfi] = *(const bf16x8*)(Yfl_g + yo);
            }
        };

        bf16x8 pbh[CPW], pbl[CPW];
        LOADY(0, pbh, pbl);
#pragma unroll
        for (int ks = 0; ks < 16; ++ks) {
            bf16x8 qbh[CPW], qbl[CPW];
            if (ks + 1 < 16) LOADY(ks + 1, qbh, qbl);
            bf16x8 ah = *(const bf16x8*)&MAh[fr][ks * 32 + kg * 8];
            bf16x8 al = *(const bf16x8*)&MAl[fr][ks * 32 + kg * 8];
#pragma unroll
            for (int nfi = 0; nfi < CPW; ++nfi) {
                accC[nfi] = MFMA(ah, pbh[nfi], accC[nfi]);
                accC[nfi] = MFMA(ah, pbl[nfi], accC[nfi]);
                accC[nfi] = MFMA(al, pbh[nfi], accC[nfi]);
            }
#pragma unroll
            for (int nfi = 0; nfi < CPW; ++nfi) { pbh[nfi] = qbh[nfi]; pbl[nfi] = qbl[nfi]; }
        }
#pragma unroll
        for (int nfi = 0; nfi < CPW; ++nfi) {
            int nf = wv + 8 * nfi;
#pragma unroll
            for (int jj = 0; jj < 4; ++jj)
                Cl[kg * 4 + jj][nf * 16 + fr] = accC[nfi][jj];
        }
        __syncthreads();
    } else {
        int nf  = wv % NF;
        int ksl = wv / NF;
        constexpr int KCH = 16 / KSPL;
        f32x4 accC;
#pragma unroll
        for (int z = 0; z < 4; ++z) accC[z] = 0.f;

        auto LOADY1 = [&](int ks, bf16x8& dh, bf16x8& dl) {
            size_t yo = ((size_t)((ibt + nf) * 16 + ks)) * 512 + (size_t)lane * 8;
            dh = *(const bf16x8*)(Yfh_g + yo);
            dl = *(const bf16x8*)(Yfl_g + yo);
        };

        bf16x8 pbh, pbl;
        LOADY1(ksl * KCH, pbh, pbl);
#pragma unroll
        for (int ki = 0; ki < KCH; ++ki) {
            int ks = ksl * KCH + ki;
            bf16x8 qbh, qbl;
            if (ki + 1 < KCH) LOADY1(ks + 1, qbh, qbl);
            bf16x8 ah = *(const bf16x8*)&MAh[fr][ks * 32 + kg * 8];
            bf16x8 al = *(const bf16x8*)&MAl[fr][ks * 32 + kg * 8];
            accC = MFMA(ah, pbh, accC);
            accC = MFMA(ah, pbl, accC);
            accC = MFMA(al, pbh, accC);
            pbh = qbh; pbl = qbl;
        }
        if (ksl == 0) {
#pragma unroll
            for (int jj = 0; jj < 4; ++jj)
                Cl[kg * 4 + jj][nf * 16 + fr] = accC[jj];
        } else {
#pragma unroll
            for (int jj = 0; jj < 4; ++jj)
                Cpart[ksl - 1][kg * 4 + jj][nf * 16 + fr] = accC[jj];
        }
        __syncthreads();
        for (int idx = t; idx < 16 * W; idx += 512) {
            int r = idx / W, c = idx - r * W;
            float s = Cl[r][c];
#pragma unroll
            for (int u = 0; u < KSPL - 1; ++u) s += Cpart[u][r][c];
            Cl[r][c] = s;
        }
        __syncthreads();
    }

    f32x4 accU[4];
#pragma unroll
    for (int ni = 0; ni < 4; ++ni)
#pragma unroll
        for (int z = 0; z < 4; ++z) accU[ni][z] = 0.f;

    int kt_bot = i_bot0 >> 5;
    constexpr int NKS2 = W / 32;

    auto LOADM = [&](int ks2, bf16x8* dh, bf16x8* dl) {
#pragma unroll
        for (int ni = 0; ni < 4; ++ni) {
            int ct = wv * 4 + ni;
            size_t mo = ((size_t)((kt_bot + ks2) * 32 + ct)) * 512 + (size_t)lane * 8;
            dh[ni] = *(const bf16x8*)(Mfh_g + mo);
            dl[ni] = *(const bf16x8*)(Mfl_g + mo);
        }
    };

    {
        bf16x8 mph[4], mpl[4];
        LOADM(0, mph, mpl);
#pragma unroll
        for (int ks2 = 0; ks2 < NKS2; ++ks2) {
            bf16x8 mqh[4], mql[4];
            if (ks2 + 1 < NKS2) LOADM(ks2 + 1, mqh, mql);
            float a8[8];
#pragma unroll
            for (int j = 0; j < 8; ++j) a8[j] = Cl[fr][ks2 * 32 + kg * 8 + j];
            bf16x8 ah2, al2;
            split8(a8, ah2, al2);
#pragma unroll
            for (int ni = 0; ni < 4; ++ni) {
                accU[ni] = MFMA(ah2, mph[ni], accU[ni]);
                accU[ni] = MFMA(ah2, mpl[ni], accU[ni]);
                accU[ni] = MFMA(al2, mph[ni], accU[ni]);
            }
#pragma unroll
            for (int ni = 0; ni < 4; ++ni) { mph[ni] = mqh[ni]; mpl[ni] = mql[ni]; }
        }
    }
#pragma unroll
    for (int ni = 0; ni < 4; ++ni) {
        int c = (wv * 4 + ni) * 16 + fr;
#pragma unroll
        for (int jj = 0; jj < 4; ++jj) {
            int il = kg * 4 + jj;
            float ma = bf2f(MAh[il][c]) + bf2f(MAl[il][c]);
            float m2 = ma - accU[ni][jj];
            u16 hu = f2bf(m2);
            MAh[il][c] = hu;
            MAl[il][c] = f2bf(m2 - bf2f(hu));
        }
    }
    __syncthreads();

    for (int idx = t; idx < 1024; idx += 512) {
        int c = idx >> 1, sub = idx & 1;
        bf16x8 hv, lv;
#pragma unroll
        for (int j = 0; j < 8; ++j) {
            hv[j] = (short)MAh[sub * 8 + j][c];
            lv[j] = (short)MAl[sub * 8 + j][c];
        }
        size_t off = ((size_t)(kt_top * 32 + (c >> 4))) * 512
                   + (size_t)((hh + sub) * 16 + (c & 15)) * 8;
        *(bf16x8*)(Mfh_g + off) = hv;
        *(bf16x8*)(Mfl_g + off) = lv;
    }
}

// ---------------------------------------------------------------------------
// Kernel 3: Qt[g][d][c] = [I - w*M]^T. 512 blocks x 256 thr, XCD-swizzled.
// A from Af, B from Mf. NEW: depth-1 prefetch across the K loop.
// ---------------------------------------------------------------------------
__global__ __launch_bounds__(256) void k_qbuild2(const u16* __restrict__ Afh,
                                                 const u16* __restrict__ Afl,
                                                 const u16* __restrict__ Mfh,
                                                 const u16* __restrict__ Mfl,
                                                 u16* __restrict__ Qt) {
    int bid = blockIdx.x;
    int qb  = (bid & 7) * 64 + (bid >> 3);    // XCD-chunked
    int t = threadIdx.x, lane = t & 63, wv = t >> 6;
    int fr = lane & 15, kg = lane >> 4;
    int g  = qb >> 6;
    int tm = (qb >> 2) & 15, tn = qb & 3;
    int c0 = tm * 32;
    int d0 = tn * 128 + wv * 32;

    const u16* Afh_g = Afh + (size_t)g * CH * CH;
    const u16* Afl_g = Afl + (size_t)g * CH * CH;
    const u16* Mfh_g = Mfh + (size_t)g * CH * CH;
    const u16* Mfl_g = Mfl + (size_t)g * CH * CH;
    u16* Qt_g = Qt + (size_t)g * CH * CH;

    f32x4 acc[2][2];
#pragma unroll
    for (int mi = 0; mi < 2; ++mi)
#pragma unroll
        for (int ni = 0; ni < 2; ++ni)
#pragma unroll
            for (int z = 0; z < 4; ++z) acc[mi][ni][z] = 0.f;

    int mt0 = c0 >> 4;
    int ct0 = d0 >> 4;

    auto LOADAB = [&](int ks, bf16x8* ah, bf16x8* al, bf16x8* bh, bf16x8* bl) {
#pragma unroll
        for (int mi = 0; mi < 2; ++mi) {
            size_t ao = ((size_t)(ks * 32 + mt0 + mi)) * 512 + (size_t)lane * 8;
            ah[mi] = *(const bf16x8*)(Afh_g + ao);
            al[mi] = *(const bf16x8*)(Afl_g + ao);
        }
#pragma unroll
        for (int ni = 0; ni < 2; ++ni) {
            size_t mo = ((size_t)(ks * 32 + ct0 + ni)) * 512 + (size_t)lane * 8;
            bh[ni] = *(const bf16x8*)(Mfh_g + mo);
            bl[ni] = *(const bf16x8*)(Mfl_g + mo);
        }
    };

    bf16x8 pah[2], pal[2], pbh[2], pbl[2];
    LOADAB(0, pah, pal, pbh, pbl);
#pragma unroll
    for (int ks = 0; ks < 16; ++ks) {
        bf16x8 qah[2], qal[2], qbh[2], qbl[2];
        if (ks + 1 < 16) LOADAB(ks + 1, qah, qal, qbh, qbl);
#pragma unroll
        for (int mi = 0; mi < 2; ++mi)
#pragma unroll
            for (int ni = 0; ni < 2; ++ni) {
                acc[mi][ni] = MFMA(pah[mi], pbh[ni], acc[mi][ni]);
                acc[mi][ni] = MFMA(pah[mi], pbl[ni], acc[mi][ni]);
                acc[mi][ni] = MFMA(pal[mi], pbh[ni], acc[mi][ni]);
            }
#pragma unroll
        for (int u = 0; u < 2; ++u) {
            pah[u] = qah[u]; pal[u] = qal[u];
            pbh[u] = qbh[u]; pbl[u] = qbl[u];
        }
    }
#pragma unroll
    for (int mi = 0; mi < 2; ++mi)
#pragma unroll
        for (int ni = 0; ni < 2; ++ni) {
            int cb2 = c0 + mi * 16 + kg * 4;
            int d   = d0 + ni * 16 + fr;
            ushort4 h4;
            h4.x = f2bf(((cb2 + 0 == d) ? 1.0f : 0.0f) - acc[mi][ni][0]);
            h4.y = f2bf(((cb2 + 1 == d) ? 1.0f : 0.0f) - acc[mi][ni][1]);
            h4.z = f2bf(((cb2 + 2 == d) ? 1.0f : 0.0f) - acc[mi][ni][2]);
            h4.w = f2bf(((cb2 + 3 == d) ? 1.0f : 0.0f) - acc[mi][ni][3]);
            *(ushort4*)(Qt_g + (size_t)d * CH + cb2) = h4;
        }
}

// ---------------------------------------------------------------------------
// Kernel 4: dbuf GEMM, counted vmcnt (T4) + setprio (T5). BK=32. (round-16)
// ---------------------------------------------------------------------------
__global__ __launch_bounds__(256) void k_gemm2(const u16* __restrict__ xb,
                                               const u16* __restrict__ Qt,
                                               float* __restrict__ out) {
    __shared__ u16 Ab[2][128 * 32];
    __shared__ u16 Bb[2][128 * 32];

    int bid0 = blockIdx.x;
    int wg = (bid0 & 7) * 128 + (bid0 >> 3);  // bijective XCD chunk; g == bid0&7
    int g  = wg >> 7;
    int r  = wg & 127;
    int tm = r >> 2;
    int tn = r & 3;

    int t    = threadIdx.x;
    int lane = t & 63;
    int wv   = t >> 6;
    int wr   = wv >> 1, wc = wv & 1;
    int fr   = lane & 15, kg = lane >> 4;

    const u16* xg  = xb + (size_t)g * BS * CH + (size_t)tm * 128 * CH;
    const u16* Qtg = Qt + (size_t)g * CH * CH + (size_t)tn * 128 * CH;
    float* og = out + (size_t)g * BS * CH + (size_t)tm * 128 * CH + (size_t)tn * 128;

    f32x4 acc[4][4];
#pragma unroll
    for (int mi = 0; mi < 4; ++mi)
#pragma unroll
        for (int ni = 0; ni < 4; ++ni)
#pragma unroll
            for (int z = 0; z < 4; ++z) acc[mi][ni][z] = 0.f;

    int srow = lane >> 2;
    int scol = (lane & 3) * 8;

    auto STAGE = [&](int p, int ks) {
        int k0 = ks * 32;
#pragma unroll
        for (int si = 0; si < 2; ++si) {
            int seg = wv * 2 + si;
            int row = seg * 16 + srow;
            gload16(xg  + (size_t)row * CH + k0 + scol, &Ab[p][seg * 512]);
            gload16(Qtg + (size_t)row * CH + k0 + scol, &Bb[p][seg * 512]);
        }
    };

    STAGE(0, 0);
    asm volatile("s_waitcnt vmcnt(0)" ::: "memory");
    __builtin_amdgcn_s_barrier();

    for (int ks = 0; ks < 16; ++ks) {
        int cur = ks & 1;
        if (ks < 15) {
            STAGE(cur ^ 1, ks + 1);
            asm volatile("s_waitcnt vmcnt(4)" ::: "memory");
        } else {
            asm volatile("s_waitcnt vmcnt(0)" ::: "memory");
        }
        __builtin_amdgcn_s_barrier();

        bf16x8 af[4], bfr[4];
#pragma unroll
        for (int mi = 0; mi < 4; ++mi)
            af[mi] = *(const bf16x8*)&Ab[cur][(wr * 64 + mi * 16 + fr) * 32 + kg * 8];
#pragma unroll
        for (int ni = 0; ni < 4; ++ni)
            bfr[ni] = *(const bf16x8*)&Bb[cur][(wc * 64 + ni * 16 + fr) * 32 + kg * 8];
        __builtin_amdgcn_s_setprio(1);
#pragma unroll
        for (int mi = 0; mi < 4; ++mi)
#pragma unroll
            for (int ni = 0; ni < 4; ++ni)
                acc[mi][ni] = MFMA(af[mi], bfr[ni], acc[mi][ni]);
        __builtin_amdgcn_s_setprio(0);

        asm volatile("" ::: "memory");
        __builtin_amdgcn_s_barrier();
    }

    int rg = lane >> 4;
#pragma unroll
    for (int mi = 0; mi < 4; ++mi)
#pragma unroll
        for (int ni = 0; ni < 4; ++ni)
#pragma unroll
            for (int rj = 0; rj < 4; ++rj) {
                int grow = wr * 64 + mi * 16 + rg * 4 + rj;
                int gcol = wc * 64 + ni * 16 + fr;
                og[(size_t)grow * CH + gcol] = acc[mi][ni][rj];
            }
}

// ---------------------------------------------------------------------------
// Fallback GEMM (fp32 A, in-staging convert) — round-5 verified.
// ---------------------------------------------------------------------------
#define LDP 40
__global__ __launch_bounds__(256) void k_gemm_f32(const float* __restrict__ x,
                                                  const u16* __restrict__ Qt,
                                                  float* __restrict__ out) {
    __shared__ u16 Al[128 * LDP];
    __shared__ u16 Bl[128 * LDP];

    int bid = blockIdx.x;
    int g  = bid >> 7;
    int tn = (bid >> 5) & 3;
    int tm = bid & 31;

    int t    = threadIdx.x;
    int lane = t & 63;
    int w    = t >> 6;
    int wr   = w >> 1, wc = w & 1;

    const float* xg = x + (size_t)g * BS * CH + (size_t)tm * 128 * CH;
    const u16* Qtg = Qt + (size_t)g * CH * CH + (size_t)tn * 128 * CH;
    float* og = out + (size_t)g * BS * CH + (size_t)tm * 128 * CH + (size_t)tn * 128;

    f32x4 acc[4][4];
#pragma unroll
    for (int mi = 0; mi < 4; ++mi)
#pragma unroll
        for (int ni = 0; ni < 4; ++ni)
#pragma unroll
            for (int z = 0; z < 4; ++z) acc[mi][ni][z] = 0.f;

    int a_k4 = t & 7;
    int a_r  = t >> 3;
    int b_n  = t & 127;
    int b_kh = t >> 7;
    int fr = lane & 15, kg = lane >> 4;

    for (int ks = 0; ks < 16; ++ks) {
        int k0 = ks * 32;
        __syncthreads();
#pragma unroll
        for (int rr = 0; rr < 4; ++rr) {
            int r = a_r + 32 * rr;
            float4 v = *(const float4*)(xg + (size_t)r * CH + k0 + a_k4 * 4);
            ushort4 h;
            h.x = f2bf(v.x); h.y = f2bf(v.y); h.z = f2bf(v.z); h.w = f2bf(v.w);
            *(ushort4*)(&Al[r * LDP + a_k4 * 4]) = h;
        }
        {
            const u16* src = Qtg + (size_t)b_n * CH + k0 + b_kh * 16;
            u16x8 lo = *(const u16x8*)src;
            u16x8 hi = *(const u16x8*)(src + 8);
            *(u16x8*)(&Bl[b_n * LDP + b_kh * 16]) = lo;
            *(u16x8*)(&Bl[b_n * LDP + b_kh * 16 + 8]) = hi;
        }
        __syncthreads();
        bf16x8 af[4], bfr[4];
#pragma unroll
        for (int mi = 0; mi < 4; ++mi)
            af[mi] = *(const bf16x8*)(&Al[(wr * 64 + mi * 16 + fr) * LDP + kg * 8]);
#pragma unroll
        for (int ni = 0; ni < 4; ++ni)
            bfr[ni] = *(const bf16x8*)(&Bl[(wc * 64 + ni * 16 + fr) * LDP + kg * 8]);
#pragma unroll
        for (int mi = 0; mi < 4; ++mi)
#pragma unroll
            for (int ni = 0; ni < 4; ++ni)
                acc[mi][ni] = MFMA(af[mi], bfr[ni], acc[mi][ni]);
    }

    int rg = lane >> 4;
#pragma unroll
    for (int mi = 0; mi < 4; ++mi)
#pragma unroll
        for (int ni = 0; ni < 4; ++ni)
#pragma unroll
            for (int rj = 0; rj < 4; ++rj) {
                int grow = wr * 64 + mi * 16 + rg * 4 + rj;
                int gcol = wc * 64 + ni * 16 + fr;
                og[(size_t)grow * CH + gcol] = acc[mi][ni][rj];
            }
}

// ---------------------------------------------------------------------------
extern "C" void kernel_launch(void* const* d_in, const int* in_sizes, int n_in,
                              void* d_out, int out_size, void* d_ws, size_t ws_size,
                              hipStream_t stream) {
    const float* x = (const float*)d_in[0];   // (8, 4096, 512)
    const float* w = (const float*)d_in[1];   // (8, 512, 512)
    float* out = (float*)d_out;

    char* ob = (char*)d_out;                  // 64 MiB scratch, dead before GEMM
    u16* Yfh = (u16*)ob;                      // [0, 4MB)
    u16* Yfl = (u16*)(ob + (4u  << 20));      // [4, 8)
    u16* Mfh = (u16*)(ob + (8u  << 20));      // [8, 12)
    u16* Mfl = (u16*)(ob + (12u << 20));      // [12, 16)
    u16* Afh = (u16*)(ob + (16u << 20));      // [16, 20)
    u16* Afl = (u16*)(ob + (20u << 20));      // [20, 24)

    int fat = (ws_size >= ((32u << 20) + (4u << 20))) ? 1 : 0;
    u16* xbp = (u16*)d_ws;
    u16* Qt  = fat ? (u16*)((char*)d_ws + (32u << 20)) : (u16*)d_ws;

    k_panelprep<<<dim3(fat ? 1152 : 128), dim3(1024), 0, stream>>>(w, x, Yfh, Yfl, Mfh, Mfl, Afh, Afl, xbp);
    k_combine<32><<<dim3(128), dim3(512), 0, stream>>>(Yfh, Yfl, Mfh, Mfl);
    k_combine<64><<<dim3(128), dim3(512), 0, stream>>>(Yfh, Yfl, Mfh, Mfl);
    k_combine<128><<<dim3(128), dim3(512), 0, stream>>>(Yfh, Yfl, Mfh, Mfl);
    k_combine<256><<<dim3(128), dim3(512), 0, stream>>>(Yfh, Yfl, Mfh, Mfl);
    k_qbuild2<<<dim3(512), dim3(256), 0, stream>>>(Afh, Afl, Mfh, Mfl, Qt);
    if (fat)
        k_gemm2<<<dim3(1024), dim3(256), 0, stream>>>(xbp, Qt, out);
    else
        k_gemm_f32<<<dim3(1024), dim3(256), 0, stream>>>(x, Qt, out);
}